// Round 2
// baseline (2916.747 us; speedup 1.0000x reference)
//
#include <hip/hip_runtime.h>

// GCN 2-layer: out = relu(Â relu(Â X W1 + b1) W2 + b2), Â = D^-1/2 (A+I) D^-1/2
// Restructured: layer1 aggregates BEFORE GEMM (F=128), layer2 AFTER (F=128).
// dinv factorization: out[dst] = dinv[dst] * Σ dinv[src]*h[src]  (+ self loop).
// edge_index is int32 (JAX default x64-disabled downcasts int64 -> int32).

#define BM 64
#define BK 32

__global__ void deg_count_kernel(const int* __restrict__ dst,
                                 float* __restrict__ deg, int E) {
    int e = blockIdx.x * blockDim.x + threadIdx.x;
    if (e < E) atomicAdd(&deg[dst[e]], 1.0f);
}

__global__ void dinv_kernel(float* __restrict__ deg, int N) {
    int i = blockIdx.x * blockDim.x + threadIdx.x;
    if (i < N) deg[i] = rsqrtf(deg[i] + 1.0f);   // self-loop adds 1
}

// Y[i][f] = X[i][f] * dinv[i]   (float4-vectorized; Fdiv4 = F/4)
__global__ void scale_rows_kernel(const float* __restrict__ X,
                                  const float* __restrict__ dinv,
                                  float* __restrict__ Y, int total, int Fdiv4) {
    int idx = blockIdx.x * blockDim.x + threadIdx.x;
    if (idx >= total) return;
    int row = idx / Fdiv4;
    float s = dinv[row];
    float4 v = ((const float4*)X)[idx];
    v.x *= s; v.y *= s; v.z *= s; v.w *= s;
    ((float4*)Y)[idx] = v;
}

// ACC[dst] += X[src] * (dinv ? dinv[src] : 1).  Half-wave (32 lanes) per edge,
// float4 per lane => 128 floats/edge.
__global__ void scatter_kernel(const int* __restrict__ src,
                               const int* __restrict__ dst,
                               const float* __restrict__ X,
                               const float* __restrict__ dinv,
                               float* __restrict__ ACC, int E) {
    int gid = blockIdx.x * blockDim.x + threadIdx.x;
    int e = gid >> 5;
    if (e >= E) return;
    int lane = gid & 31;
    int s = src[e];
    int d = dst[e];
    float nrm = dinv ? dinv[s] : 1.0f;
    float4 v = *(const float4*)(X + (size_t)s * 128 + lane * 4);
    float* p = ACC + (size_t)d * 128 + lane * 4;
    atomicAdd(p + 0, v.x * nrm);
    atomicAdd(p + 1, v.y * nrm);
    atomicAdd(p + 2, v.z * nrm);
    atomicAdd(p + 3, v.w * nrm);
}

// C[M x NCOL] = f(A[M x K] @ B[K x NCOL]); optional: A-row scale by dinv
// (scaleA), +bias, relu, output row scale by dinv (scaleOut), dual store C2.
// Tile: 64 rows x 128 cols per 256-thread block; thread = 4 rows x (4+4) cols.
__global__ __launch_bounds__(256) void gemm_kernel(
    const float* __restrict__ A, const float* __restrict__ B,
    const float* __restrict__ bias, const float* __restrict__ dinv,
    float* __restrict__ C, float* __restrict__ C2,
    int M, int K, int NCOL, int scaleA, int doRelu, int scaleOut) {
    __shared__ float sA[BM][BK + 4];   // +4 pad keeps b128 writes aligned, low conflict
    __shared__ float sB[BK][128];
    const int tid = threadIdx.x;
    const int tx = tid & 15;           // col group 0..15
    const int ty = tid >> 4;           // row group 0..15
    const int row0 = blockIdx.y * BM;
    const int col0 = blockIdx.x * 128;

    float acc[4][8];
#pragma unroll
    for (int j = 0; j < 4; j++)
#pragma unroll
        for (int c = 0; c < 8; c++) acc[j][c] = 0.0f;

    for (int k0 = 0; k0 < K; k0 += BK) {
        // stage A chunk: 64 rows x 32 k  (512 float4, 2 per thread)
#pragma unroll
        for (int i = 0; i < 2; i++) {
            int q = tid + i * 256;
            int r = q >> 3;
            int kk = (q & 7) << 2;
            int gr = row0 + r; if (gr >= M) gr = M - 1;
            float4 v = *(const float4*)(A + (size_t)gr * K + k0 + kk);
            if (scaleA) { float s = dinv[gr]; v.x *= s; v.y *= s; v.z *= s; v.w *= s; }
            *(float4*)(&sA[r][kk]) = v;
        }
        // stage B chunk: 32 k x 128 cols (1024 float4, 4 per thread)
#pragma unroll
        for (int i = 0; i < 4; i++) {
            int q = tid + i * 256;
            int r = q >> 5;
            int cc = (q & 31) << 2;
            *(float4*)(&sB[r][cc]) =
                *(const float4*)(B + (size_t)(k0 + r) * NCOL + col0 + cc);
        }
        __syncthreads();
#pragma unroll
        for (int k = 0; k < BK; k++) {
            float4 bl = *(const float4*)(&sB[k][tx * 4]);
            float4 bh = *(const float4*)(&sB[k][64 + tx * 4]);
#pragma unroll
            for (int j = 0; j < 4; j++) {
                float a = sA[ty * 4 + j][k];
                acc[j][0] += a * bl.x; acc[j][1] += a * bl.y;
                acc[j][2] += a * bl.z; acc[j][3] += a * bl.w;
                acc[j][4] += a * bh.x; acc[j][5] += a * bh.y;
                acc[j][6] += a * bh.z; acc[j][7] += a * bh.w;
            }
        }
        __syncthreads();
    }
#pragma unroll
    for (int j = 0; j < 4; j++) {
        int gr = row0 + ty * 4 + j;
        if (gr >= M) continue;
        float s = scaleOut ? dinv[gr] : 1.0f;
#pragma unroll
        for (int h = 0; h < 2; h++) {
            int c = col0 + h * 64 + tx * 4;
            float4 v;
            v.x = acc[j][h * 4 + 0]; v.y = acc[j][h * 4 + 1];
            v.z = acc[j][h * 4 + 2]; v.w = acc[j][h * 4 + 3];
            if (bias) { v.x += bias[c]; v.y += bias[c + 1];
                        v.z += bias[c + 2]; v.w += bias[c + 3]; }
            if (doRelu) { v.x = fmaxf(v.x, 0.f); v.y = fmaxf(v.y, 0.f);
                          v.z = fmaxf(v.z, 0.f); v.w = fmaxf(v.w, 0.f); }
            v.x *= s; v.y *= s; v.z *= s; v.w *= s;
            *(float4*)(C + (size_t)gr * NCOL + c) = v;
            if (C2) *(float4*)(C2 + (size_t)gr * NCOL + c) = v;
        }
    }
}

// out = relu(out * dinv[row] + bias[col])   in-place, float4
__global__ void final_kernel(float* __restrict__ OUT,
                             const float* __restrict__ dinv,
                             const float* __restrict__ bias,
                             int total, int Fdiv4) {
    int idx = blockIdx.x * blockDim.x + threadIdx.x;
    if (idx >= total) return;
    int row = idx / Fdiv4;
    int c = (idx - row * Fdiv4) * 4;
    float s = dinv[row];
    float4 v = ((float4*)OUT)[idx];
    v.x = fmaxf(v.x * s + bias[c + 0], 0.f);
    v.y = fmaxf(v.y * s + bias[c + 1], 0.f);
    v.z = fmaxf(v.z * s + bias[c + 2], 0.f);
    v.w = fmaxf(v.w * s + bias[c + 3], 0.f);
    ((float4*)OUT)[idx] = v;
}

extern "C" void kernel_launch(void* const* d_in, const int* in_sizes, int n_in,
                              void* d_out, int out_size, void* d_ws, size_t ws_size,
                              hipStream_t stream) {
    const float* x  = (const float*)d_in[0];
    const int* ei   = (const int*)d_in[1];     // int32! (JAX x64 disabled)
    const float* W1 = (const float*)d_in[2];
    const float* b1 = (const float*)d_in[3];
    const float* W2 = (const float*)d_in[4];
    const float* b2 = (const float*)d_in[5];
    float* out      = (float*)d_out;

    const int N = in_sizes[0] / 128;
    const int E = in_sizes[1] / 2;
    const int* src = ei;
    const int* dst = ei + E;

    // Workspace layout (~77 MB): dinv | H1 | Ts.  acc1 lives in d_out.
    float* ws = (float*)d_ws;
    size_t Np = ((size_t)N + 127) & ~(size_t)127;
    float* dinv = ws;                       // N (deg then dinv in-place)
    float* H1   = dinv + Np;                // N*256
    float* Ts   = H1 + (size_t)N * 256;     // N*128
    float* acc1 = out;                      // N*128 scratch, rewritten later

    // 1. degree (ws is poisoned -> must zero), then dinv = rsqrt(deg+1)
    hipMemsetAsync(dinv, 0, (size_t)N * sizeof(float), stream);
    deg_count_kernel<<<(E + 255) / 256, 256, 0, stream>>>(dst, dinv, E);
    dinv_kernel<<<(N + 255) / 256, 256, 0, stream>>>(dinv, N);

    // 2. layer-1 aggregation on X (F=128): acc1 = x*dinv (self loop) + scatter
    int tot128 = N * 32;   // N*128/4 float4s
    scale_rows_kernel<<<(tot128 + 255) / 256, 256, 0, stream>>>(x, dinv, acc1, tot128, 32);
    scatter_kernel<<<(E * 32 + 255) / 256, 256, 0, stream>>>(src, dst, x, dinv, acc1, E);

    // 3. H1 = relu((dinv .* acc1) @ W1 + b1)     [N,128]@[128,256]
    dim3 g1(2, (N + BM - 1) / BM);
    gemm_kernel<<<g1, 256, 0, stream>>>(acc1, W1, b1, dinv, H1, nullptr,
                                        N, 128, 256, /*scaleA=*/1, /*relu=*/1, /*scaleOut=*/0);

    // 4. Ts = dinv .* (H1 @ W2)   [N,256]@[256,128]; dual-store into out (self loop)
    dim3 g2(1, (N + BM - 1) / BM);
    gemm_kernel<<<g2, 256, 0, stream>>>(H1, W2, nullptr, dinv, Ts, out,
                                        N, 256, 128, /*scaleA=*/0, /*relu=*/0, /*scaleOut=*/1);

    // 5. layer-2 scatter: out[dst] += Ts[src]  (already src-scaled)
    scatter_kernel<<<(E * 32 + 255) / 256, 256, 0, stream>>>(src, dst, Ts, nullptr, out, E);

    // 6. out = relu(out * dinv + b2)
    final_kernel<<<(tot128 + 255) / 256, 256, 0, stream>>>(out, dinv, b2, tot128, 32);
}

// Round 3
// 464.796 us; speedup vs baseline: 6.2753x; 6.2753x over previous
//
#include <hip/hip_runtime.h>

// GCN 2-layer: out = relu(Â relu(Â X W1 + b1) W2 + b2), Â = D^-1/2 (A+I) D^-1/2
// R2: atomics-scatter replaced by CSR(dst) build + gather (no f32 atomics).
//   layer1 aggregates BEFORE GEMM (F=128), layer2 AFTER (F=128).
//   out[dst] = dinv[dst] * (Σ_src dinv[src]*h[src] + dinv[dst]*h[dst])
// edge_index is int32 (JAX x64 disabled downcasts int64 -> int32).

#define BM 64
#define BK 32

// ---------- CSR build ----------
__global__ void hist_kernel(const int* __restrict__ dst,
                            int* __restrict__ hist, int E) {
    int e = blockIdx.x * blockDim.x + threadIdx.x;
    if (e < E) atomicAdd(&hist[dst[e]], 1);
}

// single-block (1024 thr) exclusive scan: rowptr[0]=0, rowptr[i+1]=Σ hist[0..i]
__global__ __launch_bounds__(1024) void scan_kernel(const int* __restrict__ hist,
                                                    int* __restrict__ rowptr, int N) {
    __shared__ int sums[1024];
    const int t = threadIdx.x;
    const int chunk = (N + 1023) / 1024;
    const int start = t * chunk;
    const int end = min(start + chunk, N);
    int s = 0;
    for (int i = start; i < end; i++) s += hist[i];
    sums[t] = s;
    __syncthreads();
    for (int off = 1; off < 1024; off <<= 1) {
        int v = (t >= off) ? sums[t - off] : 0;
        __syncthreads();
        sums[t] += v;
        __syncthreads();
    }
    int run = (t == 0) ? 0 : sums[t - 1];
    if (t == 0) rowptr[0] = 0;
    for (int i = start; i < end; i++) { run += hist[i]; rowptr[i + 1] = run; }
}

__global__ void fill_kernel(const int* __restrict__ src, const int* __restrict__ dst,
                            const int* __restrict__ rowptr, int* __restrict__ cursor,
                            int* __restrict__ col, int E) {
    int e = blockIdx.x * blockDim.x + threadIdx.x;
    if (e >= E) return;
    int d = dst[e];
    int pos = rowptr[d] + atomicAdd(&cursor[d], 1);
    col[pos] = src[e];
}

// dinv[i] = rsqrt(indeg(i) + 1)   (self-loop adds 1)
__global__ void dinv_kernel(const int* __restrict__ rowptr,
                            float* __restrict__ dinv, int N) {
    int i = blockIdx.x * blockDim.x + threadIdx.x;
    if (i < N) dinv[i] = rsqrtf((float)(rowptr[i + 1] - rowptr[i]) + 1.0f);
}

// ---------- gather aggregation ----------
// OUT[r] = X[r]*w(r) + Σ_{c in-edges(r)} X[c]*w(c),  w(i)=dinv?dinv[i]:1
// half-wave (32 lanes) per row, float4/lane = 128 floats/row.
__global__ __launch_bounds__(256) void gather_kernel(
    const int* __restrict__ rowptr, const int* __restrict__ col,
    const float* __restrict__ X, const float* __restrict__ dinv,
    float* __restrict__ OUT, int N) {
    int gid = blockIdx.x * blockDim.x + threadIdx.x;
    int r = gid >> 5;
    if (r >= N) return;
    int lane = gid & 31;
    const size_t off = (size_t)lane * 4;

    float selfw = dinv ? dinv[r] : 1.0f;
    float4 v = *(const float4*)(X + (size_t)r * 128 + off);
    float4 acc;
    acc.x = v.x * selfw; acc.y = v.y * selfw;
    acc.z = v.z * selfw; acc.w = v.w * selfw;

    int beg = rowptr[r], end = rowptr[r + 1];
    int i = beg;
    for (; i + 1 < end; i += 2) {            // unroll x2: two loads in flight
        int c0 = col[i], c1 = col[i + 1];
        float w0 = dinv ? dinv[c0] : 1.0f;
        float w1 = dinv ? dinv[c1] : 1.0f;
        float4 a = *(const float4*)(X + (size_t)c0 * 128 + off);
        float4 b = *(const float4*)(X + (size_t)c1 * 128 + off);
        acc.x += a.x * w0 + b.x * w1; acc.y += a.y * w0 + b.y * w1;
        acc.z += a.z * w0 + b.z * w1; acc.w += a.w * w0 + b.w * w1;
    }
    if (i < end) {
        int c0 = col[i];
        float w0 = dinv ? dinv[c0] : 1.0f;
        float4 a = *(const float4*)(X + (size_t)c0 * 128 + off);
        acc.x += a.x * w0; acc.y += a.y * w0;
        acc.z += a.z * w0; acc.w += a.w * w0;
    }
    *(float4*)(OUT + (size_t)r * 128 + off) = acc;
}

// ---------- GEMM ----------
// C[M x NCOL] = f(A @ B); optional A-row scale (scaleA), +bias, relu,
// output row scale (scaleOut). Tile 64x128, thread = 4 rows x 8 cols.
__global__ __launch_bounds__(256) void gemm_kernel(
    const float* __restrict__ A, const float* __restrict__ B,
    const float* __restrict__ bias, const float* __restrict__ dinv,
    float* __restrict__ C,
    int M, int K, int NCOL, int scaleA, int doRelu, int scaleOut) {
    __shared__ float sA[BM][BK + 4];
    __shared__ float sB[BK][128];
    const int tid = threadIdx.x;
    const int tx = tid & 15;
    const int ty = tid >> 4;
    const int row0 = blockIdx.y * BM;
    const int col0 = blockIdx.x * 128;

    float acc[4][8];
#pragma unroll
    for (int j = 0; j < 4; j++)
#pragma unroll
        for (int c = 0; c < 8; c++) acc[j][c] = 0.0f;

    for (int k0 = 0; k0 < K; k0 += BK) {
#pragma unroll
        for (int i = 0; i < 2; i++) {
            int q = tid + i * 256;
            int r = q >> 3;
            int kk = (q & 7) << 2;
            int gr = row0 + r; if (gr >= M) gr = M - 1;
            float4 v = *(const float4*)(A + (size_t)gr * K + k0 + kk);
            if (scaleA) { float s = dinv[gr]; v.x *= s; v.y *= s; v.z *= s; v.w *= s; }
            *(float4*)(&sA[r][kk]) = v;
        }
#pragma unroll
        for (int i = 0; i < 4; i++) {
            int q = tid + i * 256;
            int r = q >> 5;
            int cc = (q & 31) << 2;
            *(float4*)(&sB[r][cc]) =
                *(const float4*)(B + (size_t)(k0 + r) * NCOL + col0 + cc);
        }
        __syncthreads();
#pragma unroll
        for (int k = 0; k < BK; k++) {
            float4 bl = *(const float4*)(&sB[k][tx * 4]);
            float4 bh = *(const float4*)(&sB[k][64 + tx * 4]);
#pragma unroll
            for (int j = 0; j < 4; j++) {
                float a = sA[ty * 4 + j][k];
                acc[j][0] += a * bl.x; acc[j][1] += a * bl.y;
                acc[j][2] += a * bl.z; acc[j][3] += a * bl.w;
                acc[j][4] += a * bh.x; acc[j][5] += a * bh.y;
                acc[j][6] += a * bh.z; acc[j][7] += a * bh.w;
            }
        }
        __syncthreads();
    }
#pragma unroll
    for (int j = 0; j < 4; j++) {
        int gr = row0 + ty * 4 + j;
        if (gr >= M) continue;
        float s = scaleOut ? dinv[gr] : 1.0f;
#pragma unroll
        for (int h = 0; h < 2; h++) {
            int c = col0 + h * 64 + tx * 4;
            float4 v;
            v.x = acc[j][h * 4 + 0]; v.y = acc[j][h * 4 + 1];
            v.z = acc[j][h * 4 + 2]; v.w = acc[j][h * 4 + 3];
            if (bias) { v.x += bias[c]; v.y += bias[c + 1];
                        v.z += bias[c + 2]; v.w += bias[c + 3]; }
            if (doRelu) { v.x = fmaxf(v.x, 0.f); v.y = fmaxf(v.y, 0.f);
                          v.z = fmaxf(v.z, 0.f); v.w = fmaxf(v.w, 0.f); }
            v.x *= s; v.y *= s; v.z *= s; v.w *= s;
            *(float4*)(C + (size_t)gr * NCOL + c) = v;
        }
    }
}

// out = relu(out * dinv[row] + bias[col])   in-place, float4
__global__ void final_kernel(float* __restrict__ OUT,
                             const float* __restrict__ dinv,
                             const float* __restrict__ bias,
                             int total, int Fdiv4) {
    int idx = blockIdx.x * blockDim.x + threadIdx.x;
    if (idx >= total) return;
    int row = idx / Fdiv4;
    int c = (idx - row * Fdiv4) * 4;
    float s = dinv[row];
    float4 v = ((float4*)OUT)[idx];
    v.x = fmaxf(v.x * s + bias[c + 0], 0.f);
    v.y = fmaxf(v.y * s + bias[c + 1], 0.f);
    v.z = fmaxf(v.z * s + bias[c + 2], 0.f);
    v.w = fmaxf(v.w * s + bias[c + 3], 0.f);
    ((float4*)OUT)[idx] = v;
}

extern "C" void kernel_launch(void* const* d_in, const int* in_sizes, int n_in,
                              void* d_out, int out_size, void* d_ws, size_t ws_size,
                              hipStream_t stream) {
    const float* x  = (const float*)d_in[0];
    const int* ei   = (const int*)d_in[1];     // int32 (JAX x64 disabled)
    const float* W1 = (const float*)d_in[2];
    const float* b1 = (const float*)d_in[3];
    const float* W2 = (const float*)d_in[4];
    const float* b2 = (const float*)d_in[5];
    float* out      = (float*)d_out;

    const int N = in_sizes[0] / 128;
    const int E = in_sizes[1] / 2;
    const int* src = ei;
    const int* dst = ei + E;

    // Workspace (~81 MB): dinv | H1 | Ts | rowptr | cursor | col
    float* ws = (float*)d_ws;
    size_t Np = ((size_t)N + 255) & ~(size_t)255;
    float* dinv   = ws;
    float* H1     = dinv + Np;                 // N*256
    float* Ts     = H1 + (size_t)N * 256;      // N*128
    int*   rowptr = (int*)(Ts + (size_t)N * 128);   // N+1
    int*   cursor = rowptr + Np;               // N
    int*   col    = cursor + Np;               // E
    float* acc1   = out;                       // N*128 scratch (rewritten by step 6)

    // 1. CSR build: hist -> scan -> fill; dinv from indeg
    hipMemsetAsync(cursor, 0, (size_t)N * sizeof(int), stream);
    hist_kernel<<<(E + 255) / 256, 256, 0, stream>>>(dst, cursor, E);
    scan_kernel<<<1, 1024, 0, stream>>>(cursor, rowptr, N);
    dinv_kernel<<<(N + 255) / 256, 256, 0, stream>>>(rowptr, dinv, N);
    hipMemsetAsync(cursor, 0, (size_t)N * sizeof(int), stream);
    fill_kernel<<<(E + 255) / 256, 256, 0, stream>>>(src, dst, rowptr, cursor, col, E);

    // 2. layer-1 aggregation (gather): acc1[r] = dinv[r]*x[r] + Σ dinv[c]*x[c]
    int gth = N * 32;
    gather_kernel<<<(gth + 255) / 256, 256, 0, stream>>>(rowptr, col, x, dinv, acc1, N);

    // 3. H1 = relu((dinv .* acc1) @ W1 + b1)     [N,128]@[128,256]
    dim3 g1(2, (N + BM - 1) / BM);
    gemm_kernel<<<g1, 256, 0, stream>>>(acc1, W1, b1, dinv, H1,
                                        N, 128, 256, 1, 1, 0);

    // 4. Ts = dinv .* (H1 @ W2)   [N,256]@[256,128]
    dim3 g2(1, (N + BM - 1) / BM);
    gemm_kernel<<<g2, 256, 0, stream>>>(H1, W2, nullptr, dinv, Ts,
                                        N, 256, 128, 0, 0, 1);

    // 5. layer-2 aggregation (gather): out[r] = Ts[r] + Σ Ts[c]  (pre-scaled)
    gather_kernel<<<(gth + 255) / 256, 256, 0, stream>>>(rowptr, col, Ts, nullptr, out, N);

    // 6. out = relu(out * dinv + b2)
    int tot128 = N * 32;
    final_kernel<<<(tot128 + 255) / 256, 256, 0, stream>>>(out, dinv, b2, tot128, 32);
}

// Round 4
// 388.985 us; speedup vs baseline: 7.4984x; 1.1949x over previous
//
#include <hip/hip_runtime.h>

// GCN 2-layer: out = relu(Â relu(Â X W1 + b1) W2 + b2), Â = D^-1/2 (A+I) D^-1/2
// R3: single-block scan (79µs @ 0.15% occ) -> 3-phase hierarchical scan;
//     gather inner loop unrolled x4.
// layer1 aggregates BEFORE GEMM (F=128), layer2 AFTER (F=128).
// edge_index is int32 (JAX x64 disabled downcasts int64 -> int32).

#define BM 64
#define BK 32
#define SCAN_CHUNK 1024

// ---------- CSR build ----------
__global__ void hist_kernel(const int* __restrict__ dst,
                            int* __restrict__ hist, int E) {
    int e = blockIdx.x * blockDim.x + threadIdx.x;
    if (e < E) atomicAdd(&hist[dst[e]], 1);
}

// phase A: per-1024-chunk sums. 256 thr/block, 4 elems/thr.
__global__ __launch_bounds__(256) void scan_sums_kernel(const int* __restrict__ hist,
                                                        int* __restrict__ bsums, int N) {
    __shared__ int red[256];
    int base = blockIdx.x * SCAN_CHUNK;
    int t = threadIdx.x;
    int s = 0;
#pragma unroll
    for (int i = 0; i < 4; i++) {
        int idx = base + t + i * 256;
        if (idx < N) s += hist[idx];
    }
    red[t] = s;
    __syncthreads();
    for (int off = 128; off > 0; off >>= 1) {
        if (t < off) red[t] += red[t + off];
        __syncthreads();
    }
    if (t == 0) bsums[blockIdx.x] = red[0];
}

// phase B: single small block scans nb (<=256) chunk sums -> inclusive.
__global__ __launch_bounds__(256) void scan_small_kernel(int* __restrict__ bsums, int nb) {
    __shared__ int s[256];
    int t = threadIdx.x;
    s[t] = (t < nb) ? bsums[t] : 0;
    __syncthreads();
    for (int off = 1; off < 256; off <<= 1) {
        int v = (t >= off) ? s[t - off] : 0;
        __syncthreads();
        s[t] += v;
        __syncthreads();
    }
    if (t < nb) bsums[t] = s[t];
}

// phase C: block-local inclusive scan of 1024 hist entries + chunk offset
// -> rowptr[i+1]; rowptr[0]=0.
__global__ __launch_bounds__(1024) void scan_apply_kernel(const int* __restrict__ hist,
                                                          const int* __restrict__ bsums,
                                                          int* __restrict__ rowptr, int N) {
    __shared__ int s[SCAN_CHUNK];
    int b = blockIdx.x;
    int t = threadIdx.x;
    int idx = b * SCAN_CHUNK + t;
    s[t] = (idx < N) ? hist[idx] : 0;
    __syncthreads();
    for (int off = 1; off < SCAN_CHUNK; off <<= 1) {
        int v = (t >= off) ? s[t - off] : 0;
        __syncthreads();
        s[t] += v;
        __syncthreads();
    }
    int base = (b > 0) ? bsums[b - 1] : 0;
    if (idx < N) rowptr[idx + 1] = s[t] + base;
    if (b == 0 && t == 0) rowptr[0] = 0;
}

__global__ void fill_kernel(const int* __restrict__ src, const int* __restrict__ dst,
                            const int* __restrict__ rowptr, int* __restrict__ cursor,
                            int* __restrict__ col, int E) {
    int e = blockIdx.x * blockDim.x + threadIdx.x;
    if (e >= E) return;
    int d = dst[e];
    int pos = rowptr[d] + atomicAdd(&cursor[d], 1);
    col[pos] = src[e];
}

// dinv[i] = rsqrt(indeg(i) + 1)   (self-loop adds 1)
__global__ void dinv_kernel(const int* __restrict__ rowptr,
                            float* __restrict__ dinv, int N) {
    int i = blockIdx.x * blockDim.x + threadIdx.x;
    if (i < N) dinv[i] = rsqrtf((float)(rowptr[i + 1] - rowptr[i]) + 1.0f);
}

// ---------- gather aggregation ----------
// OUT[r] = X[r]*w(r) + Σ_{c in-edges(r)} X[c]*w(c),  w(i)=dinv?dinv[i]:1
// half-wave (32 lanes) per row, float4/lane = 128 floats/row. Unroll x4.
__global__ __launch_bounds__(256) void gather_kernel(
    const int* __restrict__ rowptr, const int* __restrict__ col,
    const float* __restrict__ X, const float* __restrict__ dinv,
    float* __restrict__ OUT, int N) {
    int gid = blockIdx.x * blockDim.x + threadIdx.x;
    int r = gid >> 5;
    if (r >= N) return;
    int lane = gid & 31;
    const size_t off = (size_t)lane * 4;

    float selfw = dinv ? dinv[r] : 1.0f;
    float4 v = *(const float4*)(X + (size_t)r * 128 + off);
    float4 acc;
    acc.x = v.x * selfw; acc.y = v.y * selfw;
    acc.z = v.z * selfw; acc.w = v.w * selfw;

    int beg = rowptr[r], end = rowptr[r + 1];
    int i = beg;
    for (; i + 3 < end; i += 4) {            // 4 gathers in flight per lane
        int c0 = col[i], c1 = col[i + 1], c2 = col[i + 2], c3 = col[i + 3];
        float w0 = dinv ? dinv[c0] : 1.0f;
        float w1 = dinv ? dinv[c1] : 1.0f;
        float w2 = dinv ? dinv[c2] : 1.0f;
        float w3 = dinv ? dinv[c3] : 1.0f;
        float4 a = *(const float4*)(X + (size_t)c0 * 128 + off);
        float4 b = *(const float4*)(X + (size_t)c1 * 128 + off);
        float4 c = *(const float4*)(X + (size_t)c2 * 128 + off);
        float4 d = *(const float4*)(X + (size_t)c3 * 128 + off);
        acc.x += a.x * w0 + b.x * w1 + c.x * w2 + d.x * w3;
        acc.y += a.y * w0 + b.y * w1 + c.y * w2 + d.y * w3;
        acc.z += a.z * w0 + b.z * w1 + c.z * w2 + d.z * w3;
        acc.w += a.w * w0 + b.w * w1 + c.w * w2 + d.w * w3;
    }
    for (; i < end; i++) {
        int c0 = col[i];
        float w0 = dinv ? dinv[c0] : 1.0f;
        float4 a = *(const float4*)(X + (size_t)c0 * 128 + off);
        acc.x += a.x * w0; acc.y += a.y * w0;
        acc.z += a.z * w0; acc.w += a.w * w0;
    }
    *(float4*)(OUT + (size_t)r * 128 + off) = acc;
}

// ---------- GEMM ----------
// C[M x NCOL] = f(A @ B); optional A-row scale (scaleA), +bias, relu,
// output row scale (scaleOut). Tile 64x128, thread = 4 rows x 8 cols.
__global__ __launch_bounds__(256) void gemm_kernel(
    const float* __restrict__ A, const float* __restrict__ B,
    const float* __restrict__ bias, const float* __restrict__ dinv,
    float* __restrict__ C,
    int M, int K, int NCOL, int scaleA, int doRelu, int scaleOut) {
    __shared__ float sA[BM][BK + 4];
    __shared__ float sB[BK][128];
    const int tid = threadIdx.x;
    const int tx = tid & 15;
    const int ty = tid >> 4;
    const int row0 = blockIdx.y * BM;
    const int col0 = blockIdx.x * 128;

    float acc[4][8];
#pragma unroll
    for (int j = 0; j < 4; j++)
#pragma unroll
        for (int c = 0; c < 8; c++) acc[j][c] = 0.0f;

    for (int k0 = 0; k0 < K; k0 += BK) {
#pragma unroll
        for (int i = 0; i < 2; i++) {
            int q = tid + i * 256;
            int r = q >> 3;
            int kk = (q & 7) << 2;
            int gr = row0 + r; if (gr >= M) gr = M - 1;
            float4 v = *(const float4*)(A + (size_t)gr * K + k0 + kk);
            if (scaleA) { float s = dinv[gr]; v.x *= s; v.y *= s; v.z *= s; v.w *= s; }
            *(float4*)(&sA[r][kk]) = v;
        }
#pragma unroll
        for (int i = 0; i < 4; i++) {
            int q = tid + i * 256;
            int r = q >> 5;
            int cc = (q & 31) << 2;
            *(float4*)(&sB[r][cc]) =
                *(const float4*)(B + (size_t)(k0 + r) * NCOL + col0 + cc);
        }
        __syncthreads();
#pragma unroll
        for (int k = 0; k < BK; k++) {
            float4 bl = *(const float4*)(&sB[k][tx * 4]);
            float4 bh = *(const float4*)(&sB[k][64 + tx * 4]);
#pragma unroll
            for (int j = 0; j < 4; j++) {
                float a = sA[ty * 4 + j][k];
                acc[j][0] += a * bl.x; acc[j][1] += a * bl.y;
                acc[j][2] += a * bl.z; acc[j][3] += a * bl.w;
                acc[j][4] += a * bh.x; acc[j][5] += a * bh.y;
                acc[j][6] += a * bh.z; acc[j][7] += a * bh.w;
            }
        }
        __syncthreads();
    }
#pragma unroll
    for (int j = 0; j < 4; j++) {
        int gr = row0 + ty * 4 + j;
        if (gr >= M) continue;
        float s = scaleOut ? dinv[gr] : 1.0f;
#pragma unroll
        for (int h = 0; h < 2; h++) {
            int c = col0 + h * 64 + tx * 4;
            float4 v;
            v.x = acc[j][h * 4 + 0]; v.y = acc[j][h * 4 + 1];
            v.z = acc[j][h * 4 + 2]; v.w = acc[j][h * 4 + 3];
            if (bias) { v.x += bias[c]; v.y += bias[c + 1];
                        v.z += bias[c + 2]; v.w += bias[c + 3]; }
            if (doRelu) { v.x = fmaxf(v.x, 0.f); v.y = fmaxf(v.y, 0.f);
                          v.z = fmaxf(v.z, 0.f); v.w = fmaxf(v.w, 0.f); }
            v.x *= s; v.y *= s; v.z *= s; v.w *= s;
            *(float4*)(C + (size_t)gr * NCOL + c) = v;
        }
    }
}

// out = relu(out * dinv[row] + bias[col])   in-place, float4
__global__ void final_kernel(float* __restrict__ OUT,
                             const float* __restrict__ dinv,
                             const float* __restrict__ bias,
                             int total, int Fdiv4) {
    int idx = blockIdx.x * blockDim.x + threadIdx.x;
    if (idx >= total) return;
    int row = idx / Fdiv4;
    int c = (idx - row * Fdiv4) * 4;
    float s = dinv[row];
    float4 v = ((float4*)OUT)[idx];
    v.x = fmaxf(v.x * s + bias[c + 0], 0.f);
    v.y = fmaxf(v.y * s + bias[c + 1], 0.f);
    v.z = fmaxf(v.z * s + bias[c + 2], 0.f);
    v.w = fmaxf(v.w * s + bias[c + 3], 0.f);
    ((float4*)OUT)[idx] = v;
}

extern "C" void kernel_launch(void* const* d_in, const int* in_sizes, int n_in,
                              void* d_out, int out_size, void* d_ws, size_t ws_size,
                              hipStream_t stream) {
    const float* x  = (const float*)d_in[0];
    const int* ei   = (const int*)d_in[1];     // int32 (JAX x64 disabled)
    const float* W1 = (const float*)d_in[2];
    const float* b1 = (const float*)d_in[3];
    const float* W2 = (const float*)d_in[4];
    const float* b2 = (const float*)d_in[5];
    float* out      = (float*)d_out;

    const int N = in_sizes[0] / 128;
    const int E = in_sizes[1] / 2;
    const int* src = ei;
    const int* dst = ei + E;

    // Workspace (~81 MB): dinv | H1 | Ts | rowptr | cursor | col | bsums
    float* ws = (float*)d_ws;
    size_t Np = ((size_t)N + 255) & ~(size_t)255;
    float* dinv   = ws;
    float* H1     = dinv + Np;                 // N*256
    float* Ts     = H1 + (size_t)N * 256;      // N*128
    int*   rowptr = (int*)(Ts + (size_t)N * 128);   // N+1
    int*   cursor = rowptr + Np;               // N
    int*   col    = cursor + Np;               // E
    int*   bsums  = col + (((size_t)E + 255) & ~(size_t)255);  // nb (<=256)
    float* acc1   = out;                       // N*128 scratch (rewritten by step 6)

    const int nb = (N + SCAN_CHUNK - 1) / SCAN_CHUNK;   // 49 for N=50000

    // 1. CSR build: hist -> 3-phase scan -> fill; dinv from indeg
    hipMemsetAsync(cursor, 0, (size_t)N * sizeof(int), stream);
    hist_kernel<<<(E + 255) / 256, 256, 0, stream>>>(dst, cursor, E);
    scan_sums_kernel<<<nb, 256, 0, stream>>>(cursor, bsums, N);
    scan_small_kernel<<<1, 256, 0, stream>>>(bsums, nb);
    scan_apply_kernel<<<nb, 1024, 0, stream>>>(cursor, bsums, rowptr, N);
    dinv_kernel<<<(N + 255) / 256, 256, 0, stream>>>(rowptr, dinv, N);
    hipMemsetAsync(cursor, 0, (size_t)N * sizeof(int), stream);
    fill_kernel<<<(E + 255) / 256, 256, 0, stream>>>(src, dst, rowptr, cursor, col, E);

    // 2. layer-1 aggregation (gather): acc1[r] = dinv[r]*x[r] + Σ dinv[c]*x[c]
    int gth = N * 32;
    gather_kernel<<<(gth + 255) / 256, 256, 0, stream>>>(rowptr, col, x, dinv, acc1, N);

    // 3. H1 = relu((dinv .* acc1) @ W1 + b1)     [N,128]@[128,256]
    dim3 g1(2, (N + BM - 1) / BM);
    gemm_kernel<<<g1, 256, 0, stream>>>(acc1, W1, b1, dinv, H1,
                                        N, 128, 256, 1, 1, 0);

    // 4. Ts = dinv .* (H1 @ W2)   [N,256]@[256,128]
    dim3 g2(1, (N + BM - 1) / BM);
    gemm_kernel<<<g2, 256, 0, stream>>>(H1, W2, nullptr, dinv, Ts,
                                        N, 256, 128, 0, 0, 1);

    // 5. layer-2 aggregation (gather): out[r] = Ts[r] + Σ Ts[c]  (pre-scaled)
    gather_kernel<<<(gth + 255) / 256, 256, 0, stream>>>(rowptr, col, Ts, nullptr, out, N);

    // 6. out = relu(out * dinv + b2)
    int tot128 = N * 32;
    final_kernel<<<(tot128 + 255) / 256, 256, 0, stream>>>(out, dinv, b2, tot128, 32);
}

// Round 5
// 280.630 us; speedup vs baseline: 10.3936x; 1.3861x over previous
//
#include <hip/hip_runtime.h>

// GCN 2-layer, R5: bf16 payloads + MFMA GEMMs.
//   Xs = bf16(dinv ⊙ X)          (12.8 MB payload, halves gather1 traffic)
//   A1 = bf16(dinv[r]*(ΣXs[c]+Xs[r]))        (gather1, bf16 out in d_out)
//   H1 = bf16(dinv[r]*relu(A1@W1+b1))        (MFMA GEMM1, scale folded)
//   Ts = bf16(H1@W2)                          (MFMA GEMM2, plain)
//   out = relu(dinv[r]*(ΣTs[c]+Ts[r]) + b2)  (gather2, fused epilogue)
// MFMA 16x16x32 bf16 layouts (HW-verified per guide §3):
//   A: lane m=lane&15, k=quad*8+j (16B contiguous)  B: lane n=lane&15, k=quad*8+j
//   C/D: col=lane&15, row=quad*4+reg
// edge_index is int32 (JAX x64 disabled).

#define SCAN_CHUNK 1024

typedef short bf16x8 __attribute__((ext_vector_type(8)));
typedef float f32x4 __attribute__((ext_vector_type(4)));

__device__ inline unsigned short f2bf(float f) {          // RNE
    unsigned int u = __float_as_uint(f);
    u += 0x7FFF + ((u >> 16) & 1);
    return (unsigned short)(u >> 16);
}
__device__ inline float bf2f(unsigned short h) {
    return __uint_as_float(((unsigned int)h) << 16);
}

// ---------- CSR build ----------
__global__ void hist_kernel(const int* __restrict__ dst,
                            int* __restrict__ hist, int E) {
    int e = blockIdx.x * blockDim.x + threadIdx.x;
    if (e < E) atomicAdd(&hist[dst[e]], 1);
}

__global__ __launch_bounds__(256) void scan_sums_kernel(const int* __restrict__ hist,
                                                        int* __restrict__ bsums, int N) {
    __shared__ int red[256];
    int base = blockIdx.x * SCAN_CHUNK;
    int t = threadIdx.x;
    int s = 0;
#pragma unroll
    for (int i = 0; i < 4; i++) {
        int idx = base + t + i * 256;
        if (idx < N) s += hist[idx];
    }
    red[t] = s;
    __syncthreads();
    for (int off = 128; off > 0; off >>= 1) {
        if (t < off) red[t] += red[t + off];
        __syncthreads();
    }
    if (t == 0) bsums[blockIdx.x] = red[0];
}

__global__ __launch_bounds__(256) void scan_small_kernel(int* __restrict__ bsums, int nb) {
    __shared__ int s[256];
    int t = threadIdx.x;
    s[t] = (t < nb) ? bsums[t] : 0;
    __syncthreads();
    for (int off = 1; off < 256; off <<= 1) {
        int v = (t >= off) ? s[t - off] : 0;
        __syncthreads();
        s[t] += v;
        __syncthreads();
    }
    if (t < nb) bsums[t] = s[t];
}

__global__ __launch_bounds__(1024) void scan_apply_kernel(const int* __restrict__ hist,
                                                          const int* __restrict__ bsums,
                                                          int* __restrict__ rowptr, int N) {
    __shared__ int s[SCAN_CHUNK];
    int b = blockIdx.x;
    int t = threadIdx.x;
    int idx = b * SCAN_CHUNK + t;
    s[t] = (idx < N) ? hist[idx] : 0;
    __syncthreads();
    for (int off = 1; off < SCAN_CHUNK; off <<= 1) {
        int v = (t >= off) ? s[t - off] : 0;
        __syncthreads();
        s[t] += v;
        __syncthreads();
    }
    int base = (b > 0) ? bsums[b - 1] : 0;
    if (idx < N) rowptr[idx + 1] = s[t] + base;
    if (b == 0 && t == 0) rowptr[0] = 0;
}

__global__ void fill_kernel(const int* __restrict__ src, const int* __restrict__ dst,
                            const int* __restrict__ rowptr, int* __restrict__ cursor,
                            int* __restrict__ col, int E) {
    int e = blockIdx.x * blockDim.x + threadIdx.x;
    if (e >= E) return;
    int d = dst[e];
    int pos = rowptr[d] + atomicAdd(&cursor[d], 1);
    col[pos] = src[e];
}

__global__ void dinv_kernel(const int* __restrict__ rowptr,
                            float* __restrict__ dinv, int N) {
    int i = blockIdx.x * blockDim.x + threadIdx.x;
    if (i < N) dinv[i] = rsqrtf((float)(rowptr[i + 1] - rowptr[i]) + 1.0f);
}

// ---------- Xs = bf16(dinv[row] * x) ----------
__global__ void xs_kernel(const float* __restrict__ x, const float* __restrict__ dinv,
                          unsigned short* __restrict__ Xs, int total /*N*32*/) {
    int idx = blockIdx.x * blockDim.x + threadIdx.x;
    if (idx >= total) return;
    int row = idx >> 5;              // 32 float4 per 128-row
    float s = dinv[row];
    float4 v = ((const float4*)x)[idx];
    ushort4 o;
    o.x = f2bf(v.x * s); o.y = f2bf(v.y * s);
    o.z = f2bf(v.z * s); o.w = f2bf(v.w * s);
    ((ushort4*)Xs)[idx] = o;
}

// ---------- W swizzle into MFMA b-frag order ----------
// Ws[((nt*KC+kc)*64 + quad*16 + nn)*8 + j] = bf16(W[k][n]),
//   nt=n>>4, nn=n&15, kc=k>>5, quad=(k>>3)&3, j=k&7
__global__ void wswz_kernel(const float* __restrict__ W, unsigned short* __restrict__ Ws,
                            int K, int N) {
    int i = blockIdx.x * blockDim.x + threadIdx.x;
    if (i >= K * N) return;
    int k = i / N, n = i % N;
    int KC = K >> 5;
    size_t dst = ((((size_t)(n >> 4) * KC + (k >> 5)) * 64) + ((k >> 3) & 3) * 16 + (n & 15)) * 8
                 + (k & 7);
    Ws[dst] = f2bf(W[i]);
}

// ---------- gather1: A1[r] = bf16(dinv[r]*(Xs[r] + Σ Xs[c])) ----------
__global__ __launch_bounds__(256) void gather1_kernel(
    const int* __restrict__ rowptr, const int* __restrict__ col,
    const unsigned short* __restrict__ Xs, const float* __restrict__ dinv,
    unsigned short* __restrict__ A1, int N) {
    int gid = blockIdx.x * blockDim.x + threadIdx.x;
    int r = gid >> 5;
    if (r >= N) return;
    int lane = gid & 31;
    const size_t off = (size_t)lane * 4;

    ushort4 u = *(const ushort4*)(Xs + (size_t)r * 128 + off);
    float ax = bf2f(u.x), ay = bf2f(u.y), az = bf2f(u.z), aw = bf2f(u.w);

    int beg = rowptr[r], end = rowptr[r + 1];
    int i = beg;
    for (; i + 3 < end; i += 4) {
        int c0 = col[i], c1 = col[i + 1], c2 = col[i + 2], c3 = col[i + 3];
        ushort4 a = *(const ushort4*)(Xs + (size_t)c0 * 128 + off);
        ushort4 b = *(const ushort4*)(Xs + (size_t)c1 * 128 + off);
        ushort4 c = *(const ushort4*)(Xs + (size_t)c2 * 128 + off);
        ushort4 d = *(const ushort4*)(Xs + (size_t)c3 * 128 + off);
        ax += bf2f(a.x) + bf2f(b.x) + bf2f(c.x) + bf2f(d.x);
        ay += bf2f(a.y) + bf2f(b.y) + bf2f(c.y) + bf2f(d.y);
        az += bf2f(a.z) + bf2f(b.z) + bf2f(c.z) + bf2f(d.z);
        aw += bf2f(a.w) + bf2f(b.w) + bf2f(c.w) + bf2f(d.w);
    }
    for (; i < end; i++) {
        ushort4 a = *(const ushort4*)(Xs + (size_t)col[i] * 128 + off);
        ax += bf2f(a.x); ay += bf2f(a.y); az += bf2f(a.z); aw += bf2f(a.w);
    }
    float s = dinv[r];
    ushort4 o;
    o.x = f2bf(ax * s); o.y = f2bf(ay * s); o.z = f2bf(az * s); o.w = f2bf(aw * s);
    *(ushort4*)(A1 + (size_t)r * 128 + off) = o;
}

// ---------- GEMM1: H1 = bf16(dinv[r]*relu(A1@W1 + b1))   [M,128]@[128,256] ----------
__global__ __launch_bounds__(256) void gemm1_kernel(
    const unsigned short* __restrict__ A, const unsigned short* __restrict__ Ws,
    const float* __restrict__ bias, const float* __restrict__ dinv,
    unsigned short* __restrict__ H, int M) {
    int wave = threadIdx.x >> 6;
    int lane = threadIdx.x & 63;
    int mt = blockIdx.x * 4 + wave;
    if (mt * 16 >= M) return;
    int m0 = mt * 16;
    int mrow = lane & 15, quad = lane >> 4;

    bf16x8 a[4];
    const unsigned short* arow = A + (size_t)(m0 + mrow) * 128 + quad * 8;
#pragma unroll
    for (int kc = 0; kc < 4; kc++) a[kc] = *(const bf16x8*)(arow + kc * 32);

    float dv[4];
#pragma unroll
    for (int i = 0; i < 4; i++) dv[i] = dinv[m0 + quad * 4 + i];

    const bf16x8* wsv = (const bf16x8*)Ws;
    for (int nt = 0; nt < 16; nt++) {
        f32x4 acc = {0.f, 0.f, 0.f, 0.f};
#pragma unroll
        for (int kc = 0; kc < 4; kc++) {
            bf16x8 b = wsv[(nt * 4 + kc) * 64 + lane];
            acc = __builtin_amdgcn_mfma_f32_16x16x32_bf16(a[kc], b, acc, 0, 0, 0);
        }
        int colc = nt * 16 + mrow;
        float bb = bias[colc];
#pragma unroll
        for (int i = 0; i < 4; i++) {
            float v = fmaxf(acc[i] + bb, 0.f) * dv[i];
            H[(size_t)(m0 + quad * 4 + i) * 256 + colc] = f2bf(v);
        }
    }
}

// ---------- GEMM2: Ts = bf16(H1@W2)   [M,256]@[256,128] ----------
__global__ __launch_bounds__(256) void gemm2_kernel(
    const unsigned short* __restrict__ A, const unsigned short* __restrict__ Ws,
    unsigned short* __restrict__ T, int M) {
    int wave = threadIdx.x >> 6;
    int lane = threadIdx.x & 63;
    int mt = blockIdx.x * 4 + wave;
    if (mt * 16 >= M) return;
    int m0 = mt * 16;
    int mrow = lane & 15, quad = lane >> 4;

    bf16x8 a[8];
    const unsigned short* arow = A + (size_t)(m0 + mrow) * 256 + quad * 8;
#pragma unroll
    for (int kc = 0; kc < 8; kc++) a[kc] = *(const bf16x8*)(arow + kc * 32);

    const bf16x8* wsv = (const bf16x8*)Ws;
    for (int nt = 0; nt < 8; nt++) {
        f32x4 acc = {0.f, 0.f, 0.f, 0.f};
#pragma unroll
        for (int kc = 0; kc < 8; kc++) {
            bf16x8 b = wsv[(nt * 8 + kc) * 64 + lane];
            acc = __builtin_amdgcn_mfma_f32_16x16x32_bf16(a[kc], b, acc, 0, 0, 0);
        }
        int colc = nt * 16 + mrow;
#pragma unroll
        for (int i = 0; i < 4; i++)
            T[(size_t)(m0 + quad * 4 + i) * 128 + colc] = f2bf(acc[i]);
    }
}

// ---------- gather2 + fused epilogue: out = relu(dinv[r]*(Ts[r]+ΣTs[c]) + b2) ----------
__global__ __launch_bounds__(256) void gather2_kernel(
    const int* __restrict__ rowptr, const int* __restrict__ col,
    const unsigned short* __restrict__ T, const float* __restrict__ dinv,
    const float* __restrict__ bias, float* __restrict__ OUT, int N) {
    int gid = blockIdx.x * blockDim.x + threadIdx.x;
    int r = gid >> 5;
    if (r >= N) return;
    int lane = gid & 31;
    const size_t off = (size_t)lane * 4;

    ushort4 u = *(const ushort4*)(T + (size_t)r * 128 + off);
    float ax = bf2f(u.x), ay = bf2f(u.y), az = bf2f(u.z), aw = bf2f(u.w);

    int beg = rowptr[r], end = rowptr[r + 1];
    int i = beg;
    for (; i + 3 < end; i += 4) {
        int c0 = col[i], c1 = col[i + 1], c2 = col[i + 2], c3 = col[i + 3];
        ushort4 a = *(const ushort4*)(T + (size_t)c0 * 128 + off);
        ushort4 b = *(const ushort4*)(T + (size_t)c1 * 128 + off);
        ushort4 c = *(const ushort4*)(T + (size_t)c2 * 128 + off);
        ushort4 d = *(const ushort4*)(T + (size_t)c3 * 128 + off);
        ax += bf2f(a.x) + bf2f(b.x) + bf2f(c.x) + bf2f(d.x);
        ay += bf2f(a.y) + bf2f(b.y) + bf2f(c.y) + bf2f(d.y);
        az += bf2f(a.z) + bf2f(b.z) + bf2f(c.z) + bf2f(d.z);
        aw += bf2f(a.w) + bf2f(b.w) + bf2f(c.w) + bf2f(d.w);
    }
    for (; i < end; i++) {
        ushort4 a = *(const ushort4*)(T + (size_t)col[i] * 128 + off);
        ax += bf2f(a.x); ay += bf2f(a.y); az += bf2f(a.z); aw += bf2f(a.w);
    }
    float s = dinv[r];
    float4 bb = *(const float4*)(bias + off);
    float4 o;
    o.x = fmaxf(ax * s + bb.x, 0.f);
    o.y = fmaxf(ay * s + bb.y, 0.f);
    o.z = fmaxf(az * s + bb.z, 0.f);
    o.w = fmaxf(aw * s + bb.w, 0.f);
    *(float4*)(OUT + (size_t)r * 128 + off) = o;
}

extern "C" void kernel_launch(void* const* d_in, const int* in_sizes, int n_in,
                              void* d_out, int out_size, void* d_ws, size_t ws_size,
                              hipStream_t stream) {
    const float* x  = (const float*)d_in[0];
    const int* ei   = (const int*)d_in[1];     // int32 (JAX x64 disabled)
    const float* W1 = (const float*)d_in[2];
    const float* b1 = (const float*)d_in[3];
    const float* W2 = (const float*)d_in[4];
    const float* b2 = (const float*)d_in[5];
    float* out      = (float*)d_out;

    const int N = in_sizes[0] / 128;
    const int E = in_sizes[1] / 2;
    const int* src = ei;
    const int* dst = ei + E;

    // Workspace (~55 MB): dinv | H1(bf16) | Ts(bf16) | Xs(bf16) | W1s | W2s | ints
    float* ws = (float*)d_ws;
    size_t Np = ((size_t)N + 255) & ~(size_t)255;
    float*          dinv = ws;
    unsigned short* H1   = (unsigned short*)(dinv + Np);        // N*256 bf16
    unsigned short* Ts   = H1 + (size_t)N * 256;                // N*128 bf16
    unsigned short* Xs   = Ts + (size_t)N * 128;                // N*128 bf16
    unsigned short* W1s  = Xs + (size_t)N * 128;                // 128*256
    unsigned short* W2s  = W1s + 128 * 256;                     // 256*128
    int*   rowptr = (int*)(W2s + 256 * 128);                    // N+1
    int*   cursor = rowptr + Np;                                // N
    int*   col    = cursor + Np;                                // E
    int*   bsums  = col + (((size_t)E + 255) & ~(size_t)255);   // <=256
    unsigned short* A1 = (unsigned short*)d_out;                // N*128 bf16 scratch

    const int nb = (N + SCAN_CHUNK - 1) / SCAN_CHUNK;

    // 1. CSR build + dinv
    hipMemsetAsync(cursor, 0, (size_t)N * sizeof(int), stream);
    hist_kernel<<<(E + 255) / 256, 256, 0, stream>>>(dst, cursor, E);
    scan_sums_kernel<<<nb, 256, 0, stream>>>(cursor, bsums, N);
    scan_small_kernel<<<1, 256, 0, stream>>>(bsums, nb);
    scan_apply_kernel<<<nb, 1024, 0, stream>>>(cursor, bsums, rowptr, N);
    dinv_kernel<<<(N + 255) / 256, 256, 0, stream>>>(rowptr, dinv, N);
    hipMemsetAsync(cursor, 0, (size_t)N * sizeof(int), stream);
    fill_kernel<<<(E + 255) / 256, 256, 0, stream>>>(src, dst, rowptr, cursor, col, E);

    // 2. payload prep: Xs = bf16(dinv⊙x); weight swizzles
    int tot128 = N * 32;
    xs_kernel<<<(tot128 + 255) / 256, 256, 0, stream>>>(x, dinv, Xs, tot128);
    wswz_kernel<<<(128 * 256 + 255) / 256, 256, 0, stream>>>(W1, W1s, 128, 256);
    wswz_kernel<<<(256 * 128 + 255) / 256, 256, 0, stream>>>(W2, W2s, 256, 128);

    // 3. gather1 -> A1 (bf16, in d_out)
    int gth = N * 32;
    gather1_kernel<<<(gth + 255) / 256, 256, 0, stream>>>(rowptr, col, Xs, dinv, A1, N);

    // 4. GEMM1 (MFMA): H1 = bf16(dinv⊙relu(A1@W1+b1))
    int mtiles = (N + 15) / 16;
    gemm1_kernel<<<(mtiles + 3) / 4, 256, 0, stream>>>(A1, W1s, b1, dinv, H1, N);

    // 5. GEMM2 (MFMA): Ts = bf16(H1@W2)
    gemm2_kernel<<<(mtiles + 3) / 4, 256, 0, stream>>>(H1, W2s, Ts, N);

    // 6. gather2 + fused bias/relu epilogue -> out
    gather2_kernel<<<(gth + 255) / 256, 256, 0, stream>>>(rowptr, col, Ts, dinv, b2, out, N);
}

// Round 6
// 251.457 us; speedup vs baseline: 11.5994x; 1.1160x over previous
//
#include <hip/hip_runtime.h>

// GCN 2-layer, R6: bucketed CSR build (no global hist/scan/scatter-fill) +
// XCD-sliced gathers (feature slice per XCD pair -> L2-resident payload).
//   Xs = bf16(dinv ⊙ X)
//   A1 = bf16(dinv[r]*(Xs[r] + Σ Xs[c]))      (gather1, bf16, in d_out)
//   H1 = bf16(dinv[r]*relu(A1@W1+b1))         (MFMA GEMM1)
//   Ts = bf16(H1@W2)                           (MFMA GEMM2)
//   out = relu(dinv[r]*(Ts[r] + Σ Ts[c]) + b2) (gather2, fused epilogue)
// CSR: bucket b = dst>>8 (256 dsts/bucket); fixed bucket base b*cap; local
// rowptr per bucket -> rowbeg/rowend arrays (gaps between buckets are fine).
// edge_index is int32 (JAX x64 disabled).

typedef short bf16x8 __attribute__((ext_vector_type(8)));
typedef float f32x4 __attribute__((ext_vector_type(4)));

__device__ inline unsigned short f2bf(float f) {          // RNE
    unsigned int u = __float_as_uint(f);
    u += 0x7FFF + ((u >> 16) & 1);
    return (unsigned short)(u >> 16);
}
__device__ inline float bf2f(unsigned short h) {
    return __uint_as_float(((unsigned int)h) << 16);
}

// ---------- pass 1: bin edges by dst>>8 into fixed-capacity buckets ----------
// 4096 edges/block (16/thread). LDS hist -> one global reservation per bucket
// -> write (dst,src) pairs in ~21-pair contiguous runs.
__global__ __launch_bounds__(256) void bin_kernel(
    const int* __restrict__ src, const int* __restrict__ dst,
    int* __restrict__ bcur, unsigned long long* __restrict__ bbuf,
    int E, int cap) {
    __shared__ int cnt[256];
    __shared__ int base[256];
    int t = threadIdx.x;
    cnt[t] = 0;
    __syncthreads();
    int e0 = blockIdx.x * 4096;
    int s_[16], d_[16];
#pragma unroll
    for (int i = 0; i < 16; i++) {
        int e = e0 + i * 256 + t;
        if (e < E) {
            s_[i] = src[e]; d_[i] = dst[e];
            atomicAdd(&cnt[d_[i] >> 8], 1);
        } else d_[i] = -1;
    }
    __syncthreads();
    int c = cnt[t];
    base[t] = (c > 0) ? atomicAdd(&bcur[t], c) : 0;
    __syncthreads();
    cnt[t] = 0;        // reuse as local cursor
    __syncthreads();
#pragma unroll
    for (int i = 0; i < 16; i++) {
        if (d_[i] >= 0) {
            int b = d_[i] >> 8;
            int p = base[b] + atomicAdd(&cnt[b], 1);
            if (p < cap)
                bbuf[(size_t)b * cap + p] =
                    ((unsigned long long)(unsigned)d_[i] << 32) | (unsigned)s_[i];
        }
    }
}

// ---------- pass 2: per-bucket local CSR (one block per bucket) ----------
// LDS per-dst counts -> 256-wide scan -> rowbeg/rowend/dinv -> cursor fill of
// col into the bucket's contiguous region (writes stay in one L2).
__global__ __launch_bounds__(256) void bucket_csr_kernel(
    const int* __restrict__ bcur, const unsigned long long* __restrict__ bbuf,
    int* __restrict__ col, int* __restrict__ rowbeg, int* __restrict__ rowend,
    float* __restrict__ dinv, int N, int cap) {
    __shared__ int ldeg[256];
    __shared__ int lrp[256];
    int b = blockIdx.x, t = threadIdx.x;
    int cnt = min(bcur[b], cap);
    ldeg[t] = 0;
    __syncthreads();
    const unsigned long long* mybuf = bbuf + (size_t)b * cap;
    for (int i = t; i < cnt; i += 256)
        atomicAdd(&ldeg[(int)(mybuf[i] >> 32) & 255], 1);
    __syncthreads();
    int v = ldeg[t];
    lrp[t] = v;
    __syncthreads();
    for (int off = 1; off < 256; off <<= 1) {    // inclusive scan
        int u = (t >= off) ? lrp[t - off] : 0;
        __syncthreads();
        lrp[t] += u;
        __syncthreads();
    }
    int excl = lrp[t] - v;
    int r = b * 256 + t;
    int gbase = b * cap;
    if (r < N) {
        rowbeg[r] = gbase + excl;
        rowend[r] = gbase + excl + v;
        dinv[r] = rsqrtf((float)v + 1.0f);       // self-loop adds 1
    }
    ldeg[t] = excl;    // reuse as cursor
    __syncthreads();
    for (int i = t; i < cnt; i += 256) {
        unsigned long long pr = mybuf[i];
        int dl = (int)(pr >> 32) & 255;
        int p = atomicAdd(&ldeg[dl], 1);
        col[gbase + p] = (int)(pr & 0xffffffffu);
    }
}

// ---------- Xs = bf16(dinv[row] * x) ----------
__global__ void xs_kernel(const float* __restrict__ x, const float* __restrict__ dinv,
                          unsigned short* __restrict__ Xs, int total /*N*32*/) {
    int idx = blockIdx.x * blockDim.x + threadIdx.x;
    if (idx >= total) return;
    int row = idx >> 5;
    float s = dinv[row];
    float4 v = ((const float4*)x)[idx];
    ushort4 o;
    o.x = f2bf(v.x * s); o.y = f2bf(v.y * s);
    o.z = f2bf(v.z * s); o.w = f2bf(v.w * s);
    ((ushort4*)Xs)[idx] = o;
}

// ---------- W swizzle into MFMA b-frag order ----------
__global__ void wswz_kernel(const float* __restrict__ W, unsigned short* __restrict__ Ws,
                            int K, int N) {
    int i = blockIdx.x * blockDim.x + threadIdx.x;
    if (i >= K * N) return;
    int k = i / N, n = i % N;
    int KC = K >> 5;
    size_t dst = ((((size_t)(n >> 4) * KC + (k >> 5)) * 64) + ((k >> 3) & 3) * 16 + (n & 15)) * 8
                 + (k & 7);
    Ws[dst] = f2bf(W[i]);
}

// ---------- XCD-sliced gather ----------
// slice = blockIdx.x & 3 -> 32 features (64 B bf16); slice table 3.2 MB fits
// one XCD L2; round-robin dispatch puts slice s on XCDs {s, s+4}.
// 16 lanes per row, ushort2 (4 B) per lane. mode: OB!=null -> bf16 out with
// dinv scale (gather1); else f32 out with dinv*acc+bias, relu (gather2).
__global__ __launch_bounds__(256) void gather_sliced_kernel(
    const int* __restrict__ rowbeg, const int* __restrict__ rowend,
    const int* __restrict__ col, const unsigned short* __restrict__ P,
    const float* __restrict__ dinv, const float* __restrict__ bias,
    unsigned short* __restrict__ OB, float* __restrict__ OF, int N) {
    int slice = blockIdx.x & 3;
    int rb = blockIdx.x >> 2;
    int t = threadIdx.x;
    int r = rb * 16 + (t >> 4);
    if (r >= N) return;
    int fb = slice * 32 + (t & 15) * 2;
    const unsigned short* Pf = P + fb;

    ushort2 u = *(const ushort2*)(Pf + (size_t)r * 128);
    float ax = bf2f(u.x), ay = bf2f(u.y);

    int beg = rowbeg[r], end = rowend[r];
    int i = beg;
    for (; i + 3 < end; i += 4) {
        int c0 = col[i], c1 = col[i + 1], c2 = col[i + 2], c3 = col[i + 3];
        ushort2 p0 = *(const ushort2*)(Pf + (size_t)c0 * 128);
        ushort2 p1 = *(const ushort2*)(Pf + (size_t)c1 * 128);
        ushort2 p2 = *(const ushort2*)(Pf + (size_t)c2 * 128);
        ushort2 p3 = *(const ushort2*)(Pf + (size_t)c3 * 128);
        ax += bf2f(p0.x) + bf2f(p1.x) + bf2f(p2.x) + bf2f(p3.x);
        ay += bf2f(p0.y) + bf2f(p1.y) + bf2f(p2.y) + bf2f(p3.y);
    }
    for (; i < end; i++) {
        ushort2 p = *(const ushort2*)(Pf + (size_t)col[i] * 128);
        ax += bf2f(p.x); ay += bf2f(p.y);
    }
    float s = dinv[r];
    if (OB) {
        ushort2 o;
        o.x = f2bf(ax * s); o.y = f2bf(ay * s);
        *(ushort2*)(OB + (size_t)r * 128 + fb) = o;
    } else {
        float2 bb = *(const float2*)(bias + fb);
        float2 o;
        o.x = fmaxf(ax * s + bb.x, 0.f);
        o.y = fmaxf(ay * s + bb.y, 0.f);
        *(float2*)(OF + (size_t)r * 128 + fb) = o;
    }
}

// ---------- GEMM1: H1 = bf16(dinv[r]*relu(A1@W1 + b1))   [M,128]@[128,256] ----------
__global__ __launch_bounds__(256) void gemm1_kernel(
    const unsigned short* __restrict__ A, const unsigned short* __restrict__ Ws,
    const float* __restrict__ bias, const float* __restrict__ dinv,
    unsigned short* __restrict__ H, int M) {
    int wave = threadIdx.x >> 6;
    int lane = threadIdx.x & 63;
    int mt = blockIdx.x * 4 + wave;
    if (mt * 16 >= M) return;
    int m0 = mt * 16;
    int mrow = lane & 15, quad = lane >> 4;

    bf16x8 a[4];
    const unsigned short* arow = A + (size_t)(m0 + mrow) * 128 + quad * 8;
#pragma unroll
    for (int kc = 0; kc < 4; kc++) a[kc] = *(const bf16x8*)(arow + kc * 32);

    float dv[4];
#pragma unroll
    for (int i = 0; i < 4; i++) dv[i] = dinv[m0 + quad * 4 + i];

    const bf16x8* wsv = (const bf16x8*)Ws;
    for (int nt = 0; nt < 16; nt++) {
        f32x4 acc = {0.f, 0.f, 0.f, 0.f};
#pragma unroll
        for (int kc = 0; kc < 4; kc++) {
            bf16x8 b = wsv[(nt * 4 + kc) * 64 + lane];
            acc = __builtin_amdgcn_mfma_f32_16x16x32_bf16(a[kc], b, acc, 0, 0, 0);
        }
        int colc = nt * 16 + mrow;
        float bb = bias[colc];
#pragma unroll
        for (int i = 0; i < 4; i++) {
            float v = fmaxf(acc[i] + bb, 0.f) * dv[i];
            H[(size_t)(m0 + quad * 4 + i) * 256 + colc] = f2bf(v);
        }
    }
}

// ---------- GEMM2: Ts = bf16(H1@W2)   [M,256]@[256,128] ----------
__global__ __launch_bounds__(256) void gemm2_kernel(
    const unsigned short* __restrict__ A, const unsigned short* __restrict__ Ws,
    unsigned short* __restrict__ T, int M) {
    int wave = threadIdx.x >> 6;
    int lane = threadIdx.x & 63;
    int mt = blockIdx.x * 4 + wave;
    if (mt * 16 >= M) return;
    int m0 = mt * 16;
    int mrow = lane & 15, quad = lane >> 4;

    bf16x8 a[8];
    const unsigned short* arow = A + (size_t)(m0 + mrow) * 256 + quad * 8;
#pragma unroll
    for (int kc = 0; kc < 8; kc++) a[kc] = *(const bf16x8*)(arow + kc * 32);

    const bf16x8* wsv = (const bf16x8*)Ws;
    for (int nt = 0; nt < 8; nt++) {
        f32x4 acc = {0.f, 0.f, 0.f, 0.f};
#pragma unroll
        for (int kc = 0; kc < 8; kc++) {
            bf16x8 b = wsv[(nt * 8 + kc) * 64 + lane];
            acc = __builtin_amdgcn_mfma_f32_16x16x32_bf16(a[kc], b, acc, 0, 0, 0);
        }
        int colc = nt * 16 + mrow;
#pragma unroll
        for (int i = 0; i < 4; i++)
            T[(size_t)(m0 + quad * 4 + i) * 128 + colc] = f2bf(acc[i]);
    }
}

extern "C" void kernel_launch(void* const* d_in, const int* in_sizes, int n_in,
                              void* d_out, int out_size, void* d_ws, size_t ws_size,
                              hipStream_t stream) {
    const float* x  = (const float*)d_in[0];
    const int* ei   = (const int*)d_in[1];     // int32 (JAX x64 disabled)
    const float* W1 = (const float*)d_in[2];
    const float* b1 = (const float*)d_in[3];
    const float* W2 = (const float*)d_in[4];
    const float* b2 = (const float*)d_in[5];
    float* out      = (float*)d_out;

    const int N = in_sizes[0] / 128;
    const int E = in_sizes[1] / 2;
    const int* src = ei;
    const int* dst = ei + E;

    const int nbuck = (N + 255) >> 8;                       // 196
    const int cap = E / nbuck + E / (4 * nbuck) + 1024;     // ~6125, +30σ margin

    // Workspace (~66 MB): dinv | H1 | Ts | Xs | W1s | W2s | rowbeg | rowend | bcur | bbuf | col
    float* ws = (float*)d_ws;
    size_t Np = ((size_t)N + 255) & ~(size_t)255;
    float*          dinv = ws;
    unsigned short* H1   = (unsigned short*)(dinv + Np);    // N*256 bf16
    unsigned short* Ts   = H1 + (size_t)N * 256;            // N*128 bf16
    unsigned short* Xs   = Ts + (size_t)N * 128;            // N*128 bf16
    unsigned short* W1s  = Xs + (size_t)N * 128;            // 128*256
    unsigned short* W2s  = W1s + 32768;                     // 256*128
    int* rowbeg = (int*)(W2s + 32768);                      // N
    int* rowend = rowbeg + Np;                              // N
    int* bcur   = rowend + Np;                              // nbuck (<=256)
    unsigned long long* bbuf = (unsigned long long*)(bcur + 256);  // nbuck*cap pairs
    int* col    = (int*)(bbuf + (size_t)nbuck * cap);       // nbuck*cap
    unsigned short* A1 = (unsigned short*)d_out;            // N*128 bf16 scratch

    // 1. bucketed CSR build + dinv (2 kernels, 1 tiny memset)
    hipMemsetAsync(bcur, 0, 256 * sizeof(int), stream);
    bin_kernel<<<(E + 4095) / 4096, 256, 0, stream>>>(src, dst, bcur, bbuf, E, cap);
    bucket_csr_kernel<<<nbuck, 256, 0, stream>>>(bcur, bbuf, col, rowbeg, rowend,
                                                 dinv, N, cap);

    // 2. payload prep: Xs = bf16(dinv⊙x); weight swizzles
    int tot128 = N * 32;
    xs_kernel<<<(tot128 + 255) / 256, 256, 0, stream>>>(x, dinv, Xs, tot128);
    wswz_kernel<<<(128 * 256 + 255) / 256, 256, 0, stream>>>(W1, W1s, 128, 256);
    wswz_kernel<<<(256 * 128 + 255) / 256, 256, 0, stream>>>(W2, W2s, 256, 128);

    // 3. gather1 (sliced) -> A1 bf16 in d_out
    int gblocks = ((N + 15) / 16) * 4;
    gather_sliced_kernel<<<gblocks, 256, 0, stream>>>(rowbeg, rowend, col, Xs,
                                                      dinv, nullptr, A1, nullptr, N);

    // 4. GEMM1 (MFMA): H1 = bf16(dinv⊙relu(A1@W1+b1))
    int mtiles = (N + 15) / 16;
    gemm1_kernel<<<(mtiles + 3) / 4, 256, 0, stream>>>(A1, W1s, b1, dinv, H1, N);

    // 5. GEMM2 (MFMA): Ts = bf16(H1@W2)
    gemm2_kernel<<<(mtiles + 3) / 4, 256, 0, stream>>>(H1, W2s, Ts, N);

    // 6. gather2 (sliced) + fused bias/relu -> out
    gather_sliced_kernel<<<gblocks, 256, 0, stream>>>(rowbeg, rowend, col, Ts,
                                                      dinv, b2, nullptr, out, N);
}